// Round 7
// baseline (322.434 us; speedup 1.0000x reference)
//
#include <hip/hip_runtime.h>
#include <hip/hip_bf16.h>
#include <math.h>

typedef __bf16 bf16;
typedef __bf16 bf16x4 __attribute__((ext_vector_type(4)));
typedef __bf16 bf16x8 __attribute__((ext_vector_type(8)));
typedef float f32x4 __attribute__((ext_vector_type(4)));
typedef unsigned int u32;
typedef u32 __attribute__((address_space(1))) gu32;
typedef u32 __attribute__((address_space(3))) lu32;

#define TOK   16384
#define D_    256
#define HD    2048
#define QKVN  6144

// async global->LDS, 16 B/lane; LDS dest = uniform base + lane*16
#define GLDS16(g, l) __builtin_amdgcn_global_load_lds((gu32*)(g), (lu32*)(l), 16, 0, 0)
// s_waitcnt imm: vmcnt[3:0] | expcnt<<4 | lgkmcnt<<8  (expcnt=7,lgkm=15 -> no wait)
#define WAIT_VM(n) __builtin_amdgcn_s_waitcnt(0x0F70 | (n))

// ---------------------------------------------------------------------------
// Dtype probe: fp32-as-bf16 even elements are mantissa garbage -> max explodes.
// ---------------------------------------------------------------------------
__global__ void detect_dtype(const void* __restrict__ x, int* __restrict__ flag)
{
    int lane = threadIdx.x;
    const bf16* xb = (const bf16*)x;
    float m = 0.f;
    for (int i = lane; i < 4096; i += 64) {
        float v = fabsf((float)xb[2 * i]);
        if (!(v < 1e4f)) v = 1e30f;
        m = fmaxf(m, v);
    }
    for (int off = 32; off; off >>= 1) m = fmaxf(m, __shfl_xor(m, off, 64));
    if (lane == 0) *flag = (m > 1e4f) ? 1 : 0;
}

// vectorized x convert: 4 elems/thread
__global__ __launch_bounds__(256) void convert_x(
    const void* __restrict__ src, bf16* __restrict__ dst,
    const int* __restrict__ flag)
{
    int i = blockIdx.x * 256 + threadIdx.x;
    bf16x4 o;
    if (*flag) {
        f32x4 v = ((const f32x4*)src)[i];
        for (int e = 0; e < 4; e++) o[e] = (bf16)v[e];
    } else {
        o = ((const bf16x4*)src)[i];
    }
    ((bf16x4*)dst)[i] = o;
}

// all four bias vectors in one launch
__global__ __launch_bounds__(256) void fuse_bias(
    const void* __restrict__ bq, const void* __restrict__ bk,
    const void* __restrict__ bv, const void* __restrict__ bo,
    bf16* __restrict__ bqkv, bf16* __restrict__ bob,
    const int* __restrict__ flag)
{
    int i = blockIdx.x * 256 + threadIdx.x;
    if (i >= 6400) return;
    const void* src; bf16* dst; int off;
    if (i < 2048)      { src = bq; dst = bqkv;        off = i; }
    else if (i < 4096) { src = bk; dst = bqkv + 2048; off = i - 2048; }
    else if (i < 6144) { src = bv; dst = bqkv + 4096; off = i - 4096; }
    else               { src = bo; dst = bob;         off = i - 6144; }
    float v = (*flag) ? ((const float*)src)[off] : (float)((const bf16*)src)[off];
    dst[off] = (bf16)v;
}

// transpose+convert, 3 weights in one launch
__global__ __launch_bounds__(256) void transpose_cvt3(
    const void* __restrict__ Wq, const void* __restrict__ Wk,
    const void* __restrict__ Wv, bf16* __restrict__ WT,
    const int* __restrict__ flag)
{
    __shared__ float tile[32][33];
    int z = blockIdx.z;
    const void* src = (z == 0) ? Wq : (z == 1) ? Wk : Wv;
    bf16* dst = WT + (size_t)z * 2048 * 256;
    int f = *flag;
    int R = 256, C = 2048;
    int tc = blockIdx.x * 32, tr = blockIdx.y * 32;
    int lx = threadIdx.x & 31, ly = threadIdx.x >> 5;
    for (int i = 0; i < 4; i++) {
        int r = ly + i * 8;
        size_t idx = (size_t)(tr + r) * C + tc + lx;
        tile[r][lx] = f ? ((const float*)src)[idx] : (float)((const bf16*)src)[idx];
    }
    __syncthreads();
    for (int i = 0; i < 4; i++) {
        int r = ly + i * 8;
        dst[(size_t)(tc + r) * R + tr + lx] = (bf16)tile[lx][r];
    }
}

__global__ __launch_bounds__(256) void transpose_cvt(
    const void* __restrict__ src, bf16* __restrict__ dst, int R, int C,
    const int* __restrict__ flag)
{
    __shared__ float tile[32][33];
    int f = *flag;
    int tc = blockIdx.x * 32, tr = blockIdx.y * 32;
    int lx = threadIdx.x & 31, ly = threadIdx.x >> 5;
    for (int i = 0; i < 4; i++) {
        int r = ly + i * 8;
        size_t idx = (size_t)(tr + r) * C + tc + lx;
        tile[r][lx] = f ? ((const float*)src)[idx] : (float)((const bf16*)src)[idx];
    }
    __syncthreads();
    for (int i = 0; i < 4; i++) {
        int r = ly + i * 8;
        dst[(size_t)(tc + r) * R + tr + lx] = (bf16)tile[lx][r];
    }
}

// ---------------------------------------------------------------------------
// Kernel 1: qkv = x @ [Wq|Wk|Wv] + bias  (unchanged — pinned at ~94 us across
// 3 configs; evidence says HBM-write-path bound at ~2.5 TB/s for 237 MB).
// ---------------------------------------------------------------------------
__global__ __launch_bounds__(256) void proj_gemm(
    const bf16* __restrict__ X, const bf16* __restrict__ WT,
    const bf16* __restrict__ bqkv, bf16* __restrict__ qkv)
{
    __shared__ bf16 As[128 * 64];
    __shared__ bf16 Bs[128 * 64];
    int m0 = blockIdx.y * 128, n0 = blockIdx.x * 128;
    int tid = threadIdx.x, wave = tid >> 6, lane = tid & 63;
    int wm = (wave >> 1) * 64, wn = (wave & 1) * 64;
    int mrow = lane & 15, quad = lane >> 4;
    int lrow8 = lane >> 3, lslot = lane & 7;

    f32x4 acc[4][4] = {};
    for (int k0 = 0; k0 < D_; k0 += 64) {
        __syncthreads();
        for (int i = 0; i < 4; i++) {
            int rbase = wave * 32 + i * 8;
            int row = rbase + lrow8;
            int gc = lslot ^ (row & 7);
            GLDS16(&X[(size_t)(m0 + row) * D_ + k0 + gc * 8], &As[rbase * 64]);
            GLDS16(&WT[(size_t)(n0 + row) * D_ + k0 + gc * 8], &Bs[rbase * 64]);
        }
        __syncthreads();
        for (int kk = 0; kk < 64; kk += 32) {
            int slot = (((kk >> 3) + quad) ^ (mrow & 7)) * 8;
            bf16x8 af[4], bfv[4];
            for (int mt = 0; mt < 4; mt++)
                af[mt] = *(const bf16x8*)&As[(wm + mt * 16 + mrow) * 64 + slot];
            for (int nt = 0; nt < 4; nt++)
                bfv[nt] = *(const bf16x8*)&Bs[(wn + nt * 16 + mrow) * 64 + slot];
            for (int mt = 0; mt < 4; mt++)
                for (int nt = 0; nt < 4; nt++)
                    acc[mt][nt] = __builtin_amdgcn_mfma_f32_16x16x32_bf16(
                        bfv[nt], af[mt], acc[mt][nt], 0, 0, 0);
        }
    }

    for (int mt = 0; mt < 4; mt++) {
        int row = m0 + wm + mt * 16 + mrow;
        for (int nt = 0; nt < 4; nt++) {
            int col = n0 + wn + nt * 16 + quad * 4;
            bf16x4 bb = *(const bf16x4*)&bqkv[col];
            bf16x4 o;
            for (int r = 0; r < 4; r++) o[r] = (bf16)(acc[mt][nt][r] + (float)bb[r]);
            *(bf16x4*)&qkv[(size_t)row * QKVN + col] = o;
        }
    }
}

// ---------------------------------------------------------------------------
// Kernel 2: per-token 8x8 attention — SOFTWARE-PIPELINED.
// Each wave: 8 tokens, 2x12KB wave-private buffers, partial vmcnt waits
// (vmcnt(12) keeps next token's loads in flight; vmcnt(0) only for the last).
// Load-before-store issue order guarantees wait(12) implies buffer ready.
// 128-thread blocks, 48 KB LDS -> 3 blocks/CU, loads always outstanding.
// ---------------------------------------------------------------------------
__global__ __launch_bounds__(128) void attn(bf16* __restrict__ qkv)
{
    __shared__ bf16 sh[2][2][6144];   // [wave][buf][24 rows x 256]
    int wave = threadIdx.x >> 6, lane = threadIdx.x & 63;
    int h = lane >> 3, g = lane & 7;
    int t0 = (blockIdx.x * 2 + wave) * 8;

    // issue 12 glds for token t0+ti into buf[ti&1]
#define ISSUE(ti)                                                          \
    {                                                                      \
        bf16* base_ = qkv + (size_t)(t0 + (ti)) * QKVN;                    \
        bf16* dst_ = sh[wave][(ti) & 1];                                   \
        for (int i = 0; i < 12; i++) {                                     \
            int s_ = i * 64 + lane;                                        \
            int row_ = s_ >> 5, cs_ = s_ & 31;                             \
            int gc_ = cs_ ^ (row_ & 7);                                    \
            GLDS16(base_ + row_ * 256 + gc_ * 8, (char*)dst_ + i * 1024);  \
        }                                                                  \
    }

    ISSUE(0);
    ISSUE(1);

#pragma unroll
    for (int ti = 0; ti < 8; ti++) {
        if (ti < 7) WAIT_VM(12); else WAIT_VM(0);

        const bf16* sq = sh[wave][ti & 1];
        const bf16* qrow = sq + h * 256;
        const bf16* krow = sq + (8 + g) * 256;
        float s = 0.f;
        for (int c = 0; c < 32; c++) {
            bf16x8 a = *(const bf16x8*)&qrow[(c ^ h) * 8];
            bf16x8 b = *(const bf16x8*)&krow[(c ^ g) * 8];
            for (int e = 0; e < 8; e++) s += (float)a[e] * (float)b[e];
        }
        s *= 0.0625f;
        float m = s;
        for (int off = 1; off < 8; off <<= 1) m = fmaxf(m, __shfl_xor(m, off, 8));
        float p = __expf(s - m);
        float sum = p;
        for (int off = 1; off < 8; off <<= 1) sum += __shfl_xor(sum, off, 8);
        p /= sum;

        float pv[8];
        for (int g2 = 0; g2 < 8; g2++) pv[g2] = __shfl(p, h * 8 + g2, 64);

        float acc[4][8] = {};
        for (int g2 = 0; g2 < 8; g2++) {
            float pw = pv[g2];
            const bf16* vrow = sq + (16 + g2) * 256;
            for (int mm = 0; mm < 4; mm++) {
                bf16x8 v = *(const bf16x8*)&vrow[((g ^ g2) + 8 * mm) * 8];
                for (int e = 0; e < 8; e++) acc[mm][e] += pw * (float)v[e];
            }
        }
        bf16* base = qkv + (size_t)(t0 + ti) * QKVN;
        for (int mm = 0; mm < 4; mm++) {
            bf16x8 o;
            for (int e = 0; e < 8; e++) o[e] = (bf16)acc[mm][e];
            *(bf16x8*)&base[h * 256 + (g + 8 * mm) * 8] = o;
        }

        if (ti + 2 < 8) ISSUE(ti + 2);
    }
#undef ISSUE
}

// ---------------------------------------------------------------------------
// Kernel 3: out = attn_out @ Wo + bo  (M=16384, K=2048, N=256), fp32 out.
// 128x128 tile, BK=128, grid (2,128): A fetched 2x (not 4x), 64 MFMA per
// wave per barrier-pair, 64 KB LDS -> 2 blocks/CU.
// ---------------------------------------------------------------------------
__global__ __launch_bounds__(256) void out_gemm(
    const bf16* __restrict__ qkv, const bf16* __restrict__ WoT,
    const bf16* __restrict__ bob, float* __restrict__ outp)
{
    __shared__ bf16 As[128 * 128];  // 32 KB
    __shared__ bf16 Bs[128 * 128];  // 32 KB
    int m0 = blockIdx.y * 128, n0 = blockIdx.x * 128;
    int tid = threadIdx.x, wave = tid >> 6, lane = tid & 63;
    int wm = (wave >> 1) * 64, wn = (wave & 1) * 64;
    int mrow = lane & 15, quad = lane >> 4;
    int lrow16 = lane >> 4, lslot16 = lane & 15;   // 16 chunks of 16 B per row

    f32x4 acc[4][4] = {};
    for (int k0 = 0; k0 < HD; k0 += 128) {
        __syncthreads();
        for (int i = 0; i < 8; i++) {            // A: wave stages 32 rows
            int rbase = wave * 32 + i * 4;
            int row = rbase + lrow16;
            int gc = lslot16 ^ (row & 7);
            GLDS16(&qkv[(size_t)(m0 + row) * QKVN + k0 + gc * 8], &As[rbase * 128]);
        }
        for (int i = 0; i < 8; i++) {            // B: wave stages 32 rows
            int rbase = wave * 32 + i * 4;
            int row = rbase + lrow16;
            int gc = lslot16 ^ (row & 7);
            GLDS16(&WoT[(size_t)(n0 + row) * HD + k0 + gc * 8], &Bs[rbase * 128]);
        }
        __syncthreads();
        for (int kk = 0; kk < 128; kk += 32) {
            int slot = (((kk >> 3) + quad) ^ (mrow & 7)) * 8;
            bf16x8 af[4], bfv[4];
            for (int mt = 0; mt < 4; mt++)
                af[mt] = *(const bf16x8*)&As[(wm + mt * 16 + mrow) * 128 + slot];
            for (int nt = 0; nt < 4; nt++)
                bfv[nt] = *(const bf16x8*)&Bs[(wn + nt * 16 + mrow) * 128 + slot];
            for (int mt = 0; mt < 4; mt++)
                for (int nt = 0; nt < 4; nt++)
                    acc[mt][nt] = __builtin_amdgcn_mfma_f32_16x16x32_bf16(
                        bfv[nt], af[mt], acc[mt][nt], 0, 0, 0);
        }
    }

    for (int mt = 0; mt < 4; mt++) {
        int row = m0 + wm + mt * 16 + mrow;
        for (int nt = 0; nt < 4; nt++) {
            int col = n0 + wn + nt * 16 + quad * 4;
            bf16x4 bb = *(const bf16x4*)&bob[col];
            f32x4 o;
            for (int r = 0; r < 4; r++) o[r] = acc[mt][nt][r] + (float)bb[r];
            *(f32x4*)&outp[(size_t)row * D_ + col] = o;
        }
    }
}

// ---------------------------------------------------------------------------
extern "C" void kernel_launch(void* const* d_in, const int* in_sizes, int n_in,
                              void* d_out, int out_size, void* d_ws, size_t ws_size,
                              hipStream_t stream)
{
    const void* x  = d_in[0];
    const void* Wq = d_in[1];
    const void* bq = d_in[2];
    const void* Wk = d_in[3];
    const void* bk = d_in[4];
    const void* Wv = d_in[5];
    const void* bv = d_in[6];
    const void* Wo = d_in[7];
    const void* bo = d_in[8];
    float* out = (float*)d_out;

    char* ws = (char*)d_ws;
    bf16* qkv  = (bf16*)ws;                          // 201326592 B
    bf16* WT   = (bf16*)(ws + 201326592);            // 3145728 B
    bf16* WoT  = (bf16*)(ws + 204472320);            // 1048576 B
    bf16* xb   = (bf16*)(ws + 205520896);            // 8388608 B
    bf16* bqkv = (bf16*)(ws + 213909504);            // 12288 B
    bf16* bob  = (bf16*)(ws + 213921792);            // 512 B
    int*  flag = (int*)(ws + 213922304);

    detect_dtype<<<1, 64, 0, stream>>>(x, flag);

    convert_x<<<4096, 256, 0, stream>>>(x, xb, flag);
    fuse_bias<<<25, 256, 0, stream>>>(bq, bk, bv, bo, bqkv, bob, flag);
    transpose_cvt3<<<dim3(64, 8, 3), 256, 0, stream>>>(Wq, Wk, Wv, WT, flag);
    transpose_cvt<<<dim3(8, 64), 256, 0, stream>>>(Wo, WoT, 2048, 256, flag);

    proj_gemm<<<dim3(48, 128), 256, 0, stream>>>(xb, WT, bqkv, qkv);
    attn<<<1024, 128, 0, stream>>>(qkv);
    out_gemm<<<dim3(2, 128), 256, 0, stream>>>(qkv, WoT, bob, out);
}

// Round 8
// 308.084 us; speedup vs baseline: 1.0466x; 1.0466x over previous
//
#include <hip/hip_runtime.h>
#include <hip/hip_bf16.h>
#include <math.h>

typedef __bf16 bf16;
typedef __bf16 bf16x4 __attribute__((ext_vector_type(4)));
typedef __bf16 bf16x8 __attribute__((ext_vector_type(8)));
typedef float f32x4 __attribute__((ext_vector_type(4)));
typedef unsigned int u32;
typedef u32 __attribute__((address_space(1))) gu32;
typedef u32 __attribute__((address_space(3))) lu32;

#define TOK   16384
#define D_    256
#define HD    2048
#define QKVN  6144

#define GLDS16(g, l) __builtin_amdgcn_global_load_lds((gu32*)(g), (lu32*)(l), 16, 0, 0)

// ---------------------------------------------------------------------------
// Dtype probe
// ---------------------------------------------------------------------------
__global__ void detect_dtype(const void* __restrict__ x, int* __restrict__ flag)
{
    int lane = threadIdx.x;
    const bf16* xb = (const bf16*)x;
    float m = 0.f;
    for (int i = lane; i < 4096; i += 64) {
        float v = fabsf((float)xb[2 * i]);
        if (!(v < 1e4f)) v = 1e30f;
        m = fmaxf(m, v);
    }
    for (int off = 32; off; off >>= 1) m = fmaxf(m, __shfl_xor(m, off, 64));
    if (lane == 0) *flag = (m > 1e4f) ? 1 : 0;
}

__global__ __launch_bounds__(256) void convert_x(
    const void* __restrict__ src, bf16* __restrict__ dst,
    const int* __restrict__ flag)
{
    int i = blockIdx.x * 256 + threadIdx.x;
    bf16x4 o;
    if (*flag) {
        f32x4 v = ((const f32x4*)src)[i];
        for (int e = 0; e < 4; e++) o[e] = (bf16)v[e];
    } else {
        o = ((const bf16x4*)src)[i];
    }
    ((bf16x4*)dst)[i] = o;
}

__global__ __launch_bounds__(256) void fuse_bias(
    const void* __restrict__ bq, const void* __restrict__ bk,
    const void* __restrict__ bv, const void* __restrict__ bo,
    bf16* __restrict__ bqkv, bf16* __restrict__ bob,
    const int* __restrict__ flag)
{
    int i = blockIdx.x * 256 + threadIdx.x;
    if (i >= 6400) return;
    const void* src; bf16* dst; int off;
    if (i < 2048)      { src = bq; dst = bqkv;        off = i; }
    else if (i < 4096) { src = bk; dst = bqkv + 2048; off = i - 2048; }
    else if (i < 6144) { src = bv; dst = bqkv + 4096; off = i - 4096; }
    else               { src = bo; dst = bob;         off = i - 6144; }
    float v = (*flag) ? ((const float*)src)[off] : (float)((const bf16*)src)[off];
    dst[off] = (bf16)v;
}

__global__ __launch_bounds__(256) void transpose_cvt3(
    const void* __restrict__ Wq, const void* __restrict__ Wk,
    const void* __restrict__ Wv, bf16* __restrict__ WT,
    const int* __restrict__ flag)
{
    __shared__ float tile[32][33];
    int z = blockIdx.z;
    const void* src = (z == 0) ? Wq : (z == 1) ? Wk : Wv;
    bf16* dst = WT + (size_t)z * 2048 * 256;
    int f = *flag;
    int R = 256, C = 2048;
    int tc = blockIdx.x * 32, tr = blockIdx.y * 32;
    int lx = threadIdx.x & 31, ly = threadIdx.x >> 5;
    for (int i = 0; i < 4; i++) {
        int r = ly + i * 8;
        size_t idx = (size_t)(tr + r) * C + tc + lx;
        tile[r][lx] = f ? ((const float*)src)[idx] : (float)((const bf16*)src)[idx];
    }
    __syncthreads();
    for (int i = 0; i < 4; i++) {
        int r = ly + i * 8;
        dst[(size_t)(tc + r) * R + tr + lx] = (bf16)tile[lx][r];
    }
}

__global__ __launch_bounds__(256) void transpose_cvt(
    const void* __restrict__ src, bf16* __restrict__ dst, int R, int C,
    const int* __restrict__ flag)
{
    __shared__ float tile[32][33];
    int f = *flag;
    int tc = blockIdx.x * 32, tr = blockIdx.y * 32;
    int lx = threadIdx.x & 31, ly = threadIdx.x >> 5;
    for (int i = 0; i < 4; i++) {
        int r = ly + i * 8;
        size_t idx = (size_t)(tr + r) * C + tc + lx;
        tile[r][lx] = f ? ((const float*)src)[idx] : (float)((const bf16*)src)[idx];
    }
    __syncthreads();
    for (int i = 0; i < 4; i++) {
        int r = ly + i * 8;
        dst[(size_t)(tc + r) * R + tr + lx] = (bf16)tile[lx][r];
    }
}

// ---------------------------------------------------------------------------
// Kernel 1: qkv = x @ [Wq|Wk|Wv] + bias   (M=16384, K=256, N=6144)
// 128x128 tile, BK=64, glds, XOR-swizzle (0 conflicts). NEW epilogue: stage
// wave's 64x64 C-tile in LDS (stride 72: 2-way-free banks), read back 16 B
// per lane -> 128-B store segments (was 8 B/lane over 16 rows = 32-B segs).
// ---------------------------------------------------------------------------
__global__ __launch_bounds__(256) void proj_gemm(
    const bf16* __restrict__ X, const bf16* __restrict__ WT,
    const bf16* __restrict__ bqkv, bf16* __restrict__ qkv)
{
    __shared__ char smem[36864];               // union: As+Bs (32K) / epi (36K)
    bf16* As = (bf16*)smem;                    // 128*64
    bf16* Bs = (bf16*)(smem + 16384);          // 128*64
    int m0 = blockIdx.y * 128, n0 = blockIdx.x * 128;
    int tid = threadIdx.x, wave = tid >> 6, lane = tid & 63;
    int wm = (wave >> 1) * 64, wn = (wave & 1) * 64;
    int mrow = lane & 15, quad = lane >> 4;
    int lrow8 = lane >> 3, lslot = lane & 7;

    f32x4 acc[4][4] = {};
    for (int k0 = 0; k0 < D_; k0 += 64) {
        __syncthreads();
        for (int i = 0; i < 4; i++) {
            int rbase = wave * 32 + i * 8;
            int row = rbase + lrow8;
            int gc = lslot ^ (row & 7);
            GLDS16(&X[(size_t)(m0 + row) * D_ + k0 + gc * 8], &As[rbase * 64]);
            GLDS16(&WT[(size_t)(n0 + row) * D_ + k0 + gc * 8], &Bs[rbase * 64]);
        }
        __syncthreads();
        for (int kk = 0; kk < 64; kk += 32) {
            int slot = (((kk >> 3) + quad) ^ (mrow & 7)) * 8;
            bf16x8 af[4], bfv[4];
            for (int mt = 0; mt < 4; mt++)
                af[mt] = *(const bf16x8*)&As[(wm + mt * 16 + mrow) * 64 + slot];
            for (int nt = 0; nt < 4; nt++)
                bfv[nt] = *(const bf16x8*)&Bs[(wn + nt * 16 + mrow) * 64 + slot];
            for (int mt = 0; mt < 4; mt++)
                for (int nt = 0; nt < 4; nt++)
                    acc[mt][nt] = __builtin_amdgcn_mfma_f32_16x16x32_bf16(
                        bfv[nt], af[mt], acc[mt][nt], 0, 0, 0);
        }
    }

    // epilogue via LDS: repurpose smem (all K-loop LDS reads done after sync)
    __syncthreads();
    bf16* ep = (bf16*)smem + wave * (64 * 72);
    for (int mt = 0; mt < 4; mt++) {
        for (int nt = 0; nt < 4; nt++) {
            int col = n0 + wn + nt * 16 + quad * 4;
            bf16x4 bb = *(const bf16x4*)&bqkv[col];
            bf16x4 o;
            for (int r = 0; r < 4; r++) o[r] = (bf16)(acc[mt][nt][r] + (float)bb[r]);
            *(bf16x4*)&ep[(mt * 16 + mrow) * 72 + nt * 16 + quad * 4] = o;
        }
    }
    __syncthreads();
    for (int i = 0; i < 8; i++) {
        int r = i * 8 + (lane >> 3);           // row within wave tile
        int cb = (lane & 7) * 8;               // col elem
        bf16x8 val = *(const bf16x8*)&ep[r * 72 + cb];
        *(bf16x8*)&qkv[(size_t)(m0 + wm + r) * QKVN + n0 + wn + cb] = val;
    }
}

// ---------------------------------------------------------------------------
// Kernel 2: per-token 8x8 attention — REGISTERS ONLY, 1 token per wave.
// Zero LDS -> occupancy bounded only by VGPR (~8 waves/SIMD). 16384 waves.
// Lane (h,g): score q[h].k[g]; width-8 shuffle softmax; PV owns out chunks
// (g+8m) -> 128-B contiguous store segments per 8-lane group.
// ---------------------------------------------------------------------------
__global__ __launch_bounds__(256) void attn(bf16* __restrict__ qkv)
{
    int wave = threadIdx.x >> 6, lane = threadIdx.x & 63;
    int h = lane >> 3, g = lane & 7;
    int t = blockIdx.x * 4 + wave;

    const bf16* qrow = qkv + (size_t)t * QKVN + h * D_;
    const bf16* krow = qkv + (size_t)t * QKVN + HD + g * D_;
    const bf16* vbase = qkv + (size_t)t * QKVN + 2 * HD;

    float s = 0.f;
    for (int c = 0; c < 32; c++) {
        bf16x8 a = *(const bf16x8*)&qrow[c * 8];
        bf16x8 b = *(const bf16x8*)&krow[c * 8];
        for (int e = 0; e < 8; e++) s += (float)a[e] * (float)b[e];
    }
    s *= 0.0625f;
    float m = s;
    for (int off = 1; off < 8; off <<= 1) m = fmaxf(m, __shfl_xor(m, off, 8));
    float p = __expf(s - m);
    float sum = p;
    for (int off = 1; off < 8; off <<= 1) sum += __shfl_xor(sum, off, 8);
    p /= sum;

    float pv[8];
    for (int g2 = 0; g2 < 8; g2++) pv[g2] = __shfl(p, h * 8 + g2, 64);

    float acc[4][8] = {};
    for (int g2 = 0; g2 < 8; g2++) {
        float pw = pv[g2];
        const bf16* vrow = vbase + g2 * D_;
        for (int mm = 0; mm < 4; mm++) {
            bf16x8 v = *(const bf16x8*)&vrow[(g + 8 * mm) * 8];
            for (int e = 0; e < 8; e++) acc[mm][e] += pw * (float)v[e];
        }
    }
    bf16* obase = qkv + (size_t)t * QKVN + h * D_;
    for (int mm = 0; mm < 4; mm++) {
        bf16x8 o;
        for (int e = 0; e < 8; e++) o[e] = (bf16)acc[mm][e];
        *(bf16x8*)&obase[(g + 8 * mm) * 8] = o;
    }
}

// ---------------------------------------------------------------------------
// Kernel 3: out = attn_out @ Wo + bo  (M=16384, K=2048, N=256), fp32 out.
// 128x128 tile, BK=128 (unchanged from round 7).
// ---------------------------------------------------------------------------
__global__ __launch_bounds__(256) void out_gemm(
    const bf16* __restrict__ qkv, const bf16* __restrict__ WoT,
    const bf16* __restrict__ bob, float* __restrict__ outp)
{
    __shared__ bf16 As[128 * 128];
    __shared__ bf16 Bs[128 * 128];
    int m0 = blockIdx.y * 128, n0 = blockIdx.x * 128;
    int tid = threadIdx.x, wave = tid >> 6, lane = tid & 63;
    int wm = (wave >> 1) * 64, wn = (wave & 1) * 64;
    int mrow = lane & 15, quad = lane >> 4;
    int lrow16 = lane >> 4, lslot16 = lane & 15;

    f32x4 acc[4][4] = {};
    for (int k0 = 0; k0 < HD; k0 += 128) {
        __syncthreads();
        for (int i = 0; i < 8; i++) {
            int rbase = wave * 32 + i * 4;
            int row = rbase + lrow16;
            int gc = lslot16 ^ (row & 7);
            GLDS16(&qkv[(size_t)(m0 + row) * QKVN + k0 + gc * 8], &As[rbase * 128]);
        }
        for (int i = 0; i < 8; i++) {
            int rbase = wave * 32 + i * 4;
            int row = rbase + lrow16;
            int gc = lslot16 ^ (row & 7);
            GLDS16(&WoT[(size_t)(n0 + row) * HD + k0 + gc * 8], &Bs[rbase * 128]);
        }
        __syncthreads();
        for (int kk = 0; kk < 128; kk += 32) {
            int slot = (((kk >> 3) + quad) ^ (mrow & 7)) * 8;
            bf16x8 af[4], bfv[4];
            for (int mt = 0; mt < 4; mt++)
                af[mt] = *(const bf16x8*)&As[(wm + mt * 16 + mrow) * 128 + slot];
            for (int nt = 0; nt < 4; nt++)
                bfv[nt] = *(const bf16x8*)&Bs[(wn + nt * 16 + mrow) * 128 + slot];
            for (int mt = 0; mt < 4; mt++)
                for (int nt = 0; nt < 4; nt++)
                    acc[mt][nt] = __builtin_amdgcn_mfma_f32_16x16x32_bf16(
                        bfv[nt], af[mt], acc[mt][nt], 0, 0, 0);
        }
    }

    for (int mt = 0; mt < 4; mt++) {
        int row = m0 + wm + mt * 16 + mrow;
        for (int nt = 0; nt < 4; nt++) {
            int col = n0 + wn + nt * 16 + quad * 4;
            bf16x4 bb = *(const bf16x4*)&bob[col];
            f32x4 o;
            for (int r = 0; r < 4; r++) o[r] = acc[mt][nt][r] + (float)bb[r];
            *(f32x4*)&outp[(size_t)row * D_ + col] = o;
        }
    }
}

// ---------------------------------------------------------------------------
extern "C" void kernel_launch(void* const* d_in, const int* in_sizes, int n_in,
                              void* d_out, int out_size, void* d_ws, size_t ws_size,
                              hipStream_t stream)
{
    const void* x  = d_in[0];
    const void* Wq = d_in[1];
    const void* bq = d_in[2];
    const void* Wk = d_in[3];
    const void* bk = d_in[4];
    const void* Wv = d_in[5];
    const void* bv = d_in[6];
    const void* Wo = d_in[7];
    const void* bo = d_in[8];
    float* out = (float*)d_out;

    char* ws = (char*)d_ws;
    bf16* qkv  = (bf16*)ws;                          // 201326592 B
    bf16* WT   = (bf16*)(ws + 201326592);            // 3145728 B
    bf16* WoT  = (bf16*)(ws + 204472320);            // 1048576 B
    bf16* xb   = (bf16*)(ws + 205520896);            // 8388608 B
    bf16* bqkv = (bf16*)(ws + 213909504);            // 12288 B
    bf16* bob  = (bf16*)(ws + 213921792);            // 512 B
    int*  flag = (int*)(ws + 213922304);

    detect_dtype<<<1, 64, 0, stream>>>(x, flag);

    convert_x<<<4096, 256, 0, stream>>>(x, xb, flag);
    fuse_bias<<<25, 256, 0, stream>>>(bq, bk, bv, bo, bqkv, bob, flag);
    transpose_cvt3<<<dim3(64, 8, 3), 256, 0, stream>>>(Wq, Wk, Wv, WT, flag);
    transpose_cvt<<<dim3(8, 64), 256, 0, stream>>>(Wo, WoT, 2048, 256, flag);

    proj_gemm<<<dim3(48, 128), 256, 0, stream>>>(xb, WT, bqkv, qkv);
    attn<<<4096, 256, 0, stream>>>(qkv);
    out_gemm<<<dim3(2, 128), 256, 0, stream>>>(qkv, WoT, bob, out);
}

// Round 9
// 277.403 us; speedup vs baseline: 1.1623x; 1.1106x over previous
//
#include <hip/hip_runtime.h>
#include <hip/hip_bf16.h>
#include <math.h>

typedef __bf16 bf16;
typedef __bf16 bf16x4 __attribute__((ext_vector_type(4)));
typedef __bf16 bf16x8 __attribute__((ext_vector_type(8)));
typedef float f32x4 __attribute__((ext_vector_type(4)));
typedef unsigned int u32;
typedef u32 __attribute__((address_space(1))) gu32;
typedef u32 __attribute__((address_space(3))) lu32;

#define TOK   16384
#define D_    256
#define HD    2048
#define QKVN  6144

#define GLDS16(g, l) __builtin_amdgcn_global_load_lds((gu32*)(g), (lu32*)(l), 16, 0, 0)
// s_waitcnt imm: vmcnt[3:0] | expcnt<<4 | lgkmcnt<<8  (expcnt=7,lgkm=15 -> no wait)
#define WAIT_VM(n) __builtin_amdgcn_s_waitcnt(0x0F70 | (n))

// ---------------------------------------------------------------------------
// Dtype probe
// ---------------------------------------------------------------------------
__global__ void detect_dtype(const void* __restrict__ x, int* __restrict__ flag)
{
    int lane = threadIdx.x;
    const bf16* xb = (const bf16*)x;
    float m = 0.f;
    for (int i = lane; i < 4096; i += 64) {
        float v = fabsf((float)xb[2 * i]);
        if (!(v < 1e4f)) v = 1e30f;
        m = fmaxf(m, v);
    }
    for (int off = 32; off; off >>= 1) m = fmaxf(m, __shfl_xor(m, off, 64));
    if (lane == 0) *flag = (m > 1e4f) ? 1 : 0;
}

__global__ __launch_bounds__(256) void convert_x(
    const void* __restrict__ src, bf16* __restrict__ dst,
    const int* __restrict__ flag)
{
    int i = blockIdx.x * 256 + threadIdx.x;
    bf16x4 o;
    if (*flag) {
        f32x4 v = ((const f32x4*)src)[i];
        for (int e = 0; e < 4; e++) o[e] = (bf16)v[e];
    } else {
        o = ((const bf16x4*)src)[i];
    }
    ((bf16x4*)dst)[i] = o;
}

__global__ __launch_bounds__(256) void fuse_bias(
    const void* __restrict__ bq, const void* __restrict__ bk,
    const void* __restrict__ bv, const void* __restrict__ bo,
    bf16* __restrict__ bqkv, bf16* __restrict__ bob,
    const int* __restrict__ flag)
{
    int i = blockIdx.x * 256 + threadIdx.x;
    if (i >= 6400) return;
    const void* src; bf16* dst; int off;
    if (i < 2048)      { src = bq; dst = bqkv;        off = i; }
    else if (i < 4096) { src = bk; dst = bqkv + 2048; off = i - 2048; }
    else if (i < 6144) { src = bv; dst = bqkv + 4096; off = i - 4096; }
    else               { src = bo; dst = bob;         off = i - 6144; }
    float v = (*flag) ? ((const float*)src)[off] : (float)((const bf16*)src)[off];
    dst[off] = (bf16)v;
}

__global__ __launch_bounds__(256) void transpose_cvt3(
    const void* __restrict__ Wq, const void* __restrict__ Wk,
    const void* __restrict__ Wv, bf16* __restrict__ WT,
    const int* __restrict__ flag)
{
    __shared__ float tile[32][33];
    int z = blockIdx.z;
    const void* src = (z == 0) ? Wq : (z == 1) ? Wk : Wv;
    bf16* dst = WT + (size_t)z * 2048 * 256;
    int f = *flag;
    int R = 256, C = 2048;
    int tc = blockIdx.x * 32, tr = blockIdx.y * 32;
    int lx = threadIdx.x & 31, ly = threadIdx.x >> 5;
    for (int i = 0; i < 4; i++) {
        int r = ly + i * 8;
        size_t idx = (size_t)(tr + r) * C + tc + lx;
        tile[r][lx] = f ? ((const float*)src)[idx] : (float)((const bf16*)src)[idx];
    }
    __syncthreads();
    for (int i = 0; i < 4; i++) {
        int r = ly + i * 8;
        dst[(size_t)(tc + r) * R + tr + lx] = (bf16)tile[lx][r];
    }
}

__global__ __launch_bounds__(256) void transpose_cvt(
    const void* __restrict__ src, bf16* __restrict__ dst, int R, int C,
    const int* __restrict__ flag)
{
    __shared__ float tile[32][33];
    int f = *flag;
    int tc = blockIdx.x * 32, tr = blockIdx.y * 32;
    int lx = threadIdx.x & 31, ly = threadIdx.x >> 5;
    for (int i = 0; i < 4; i++) {
        int r = ly + i * 8;
        size_t idx = (size_t)(tr + r) * C + tc + lx;
        tile[r][lx] = f ? ((const float*)src)[idx] : (float)((const bf16*)src)[idx];
    }
    __syncthreads();
    for (int i = 0; i < 4; i++) {
        int r = ly + i * 8;
        dst[(size_t)(tc + r) * R + tr + lx] = (bf16)tile[lx][r];
    }
}

// ---------------------------------------------------------------------------
// Kernel 1: qkv = x @ [Wq|Wk|Wv] + bias  (unchanged from round 8)
// ---------------------------------------------------------------------------
__global__ __launch_bounds__(256) void proj_gemm(
    const bf16* __restrict__ X, const bf16* __restrict__ WT,
    const bf16* __restrict__ bqkv, bf16* __restrict__ qkv)
{
    __shared__ char smem[36864];               // union: As+Bs (32K) / epi (36K)
    bf16* As = (bf16*)smem;                    // 128*64
    bf16* Bs = (bf16*)(smem + 16384);          // 128*64
    int m0 = blockIdx.y * 128, n0 = blockIdx.x * 128;
    int tid = threadIdx.x, wave = tid >> 6, lane = tid & 63;
    int wm = (wave >> 1) * 64, wn = (wave & 1) * 64;
    int mrow = lane & 15, quad = lane >> 4;
    int lrow8 = lane >> 3, lslot = lane & 7;

    f32x4 acc[4][4] = {};
    for (int k0 = 0; k0 < D_; k0 += 64) {
        __syncthreads();
        for (int i = 0; i < 4; i++) {
            int rbase = wave * 32 + i * 8;
            int row = rbase + lrow8;
            int gc = lslot ^ (row & 7);
            GLDS16(&X[(size_t)(m0 + row) * D_ + k0 + gc * 8], &As[rbase * 64]);
            GLDS16(&WT[(size_t)(n0 + row) * D_ + k0 + gc * 8], &Bs[rbase * 64]);
        }
        __syncthreads();
        for (int kk = 0; kk < 64; kk += 32) {
            int slot = (((kk >> 3) + quad) ^ (mrow & 7)) * 8;
            bf16x8 af[4], bfv[4];
            for (int mt = 0; mt < 4; mt++)
                af[mt] = *(const bf16x8*)&As[(wm + mt * 16 + mrow) * 64 + slot];
            for (int nt = 0; nt < 4; nt++)
                bfv[nt] = *(const bf16x8*)&Bs[(wn + nt * 16 + mrow) * 64 + slot];
            for (int mt = 0; mt < 4; mt++)
                for (int nt = 0; nt < 4; nt++)
                    acc[mt][nt] = __builtin_amdgcn_mfma_f32_16x16x32_bf16(
                        bfv[nt], af[mt], acc[mt][nt], 0, 0, 0);
        }
    }

    __syncthreads();
    bf16* ep = (bf16*)smem + wave * (64 * 72);
    for (int mt = 0; mt < 4; mt++) {
        for (int nt = 0; nt < 4; nt++) {
            int col = n0 + wn + nt * 16 + quad * 4;
            bf16x4 bb = *(const bf16x4*)&bqkv[col];
            bf16x4 o;
            for (int r = 0; r < 4; r++) o[r] = (bf16)(acc[mt][nt][r] + (float)bb[r]);
            *(bf16x4*)&ep[(mt * 16 + mrow) * 72 + nt * 16 + quad * 4] = o;
        }
    }
    __syncthreads();
    for (int i = 0; i < 8; i++) {
        int r = i * 8 + (lane >> 3);
        int cb = (lane & 7) * 8;
        bf16x8 val = *(const bf16x8*)&ep[r * 72 + cb];
        *(bf16x8*)&qkv[(size_t)(m0 + wm + r) * QKVN + n0 + wn + cb] = val;
    }
}

// ---------------------------------------------------------------------------
// Kernel 2: per-token 8x8 attention — glds-staged with SPLIT vmcnt waits.
// Per wave per token: issue 12 glds (q+k rows first, v rows last);
// WAIT_VM(4) retires exactly the 8 q+k loads (v stays in flight through
// score + softmax ~2000 cyc); WAIT_VM(0) before PV. All counted VMEM ops
// are glds intrinsics (program-ordered). 4 waves x 12 KB = 48 KB ->
// 3 blocks/CU (37% occ). XOR swizzle: conflict-free LDS reads (r5-verified).
// 4 independent score accumulators for FMA-chain ILP.
// ---------------------------------------------------------------------------
__global__ __launch_bounds__(256) void attn(bf16* __restrict__ qkv)
{
    __shared__ bf16 sh[4][6144];   // per wave: rows 0-7 q, 8-15 k, 16-23 v
    int wave = threadIdx.x >> 6, lane = threadIdx.x & 63;
    bf16* sq = sh[wave];
    int h = lane >> 3, g = lane & 7;
    int t0 = blockIdx.x * 16 + wave * 4;

    for (int ti = 0; ti < 4; ti++) {
        int t = t0 + ti;
        bf16* base = qkv + (size_t)t * QKVN;
        // 12 glds: i 0-7 -> q+k rows 0-15; i 8-11 -> v rows 16-23
        for (int i = 0; i < 12; i++) {
            int s = i * 64 + lane;
            int row = s >> 5, cs = s & 31;
            int gc = cs ^ (row & 7);
            GLDS16(base + row * 256 + gc * 8, (char*)sq + i * 1024);
        }
        WAIT_VM(4);   // q+k resident; v (4 newest) still in flight

        const bf16* qrow = sq + h * 256;
        const bf16* krow = sq + (8 + g) * 256;
        float s0 = 0.f, s1 = 0.f, s2 = 0.f, s3 = 0.f;
        for (int c = 0; c < 32; c += 4) {
            bf16x8 a0 = *(const bf16x8*)&qrow[((c + 0) ^ h) * 8];
            bf16x8 b0 = *(const bf16x8*)&krow[((c + 0) ^ g) * 8];
            bf16x8 a1 = *(const bf16x8*)&qrow[((c + 1) ^ h) * 8];
            bf16x8 b1 = *(const bf16x8*)&krow[((c + 1) ^ g) * 8];
            bf16x8 a2 = *(const bf16x8*)&qrow[((c + 2) ^ h) * 8];
            bf16x8 b2 = *(const bf16x8*)&krow[((c + 2) ^ g) * 8];
            bf16x8 a3 = *(const bf16x8*)&qrow[((c + 3) ^ h) * 8];
            bf16x8 b3 = *(const bf16x8*)&krow[((c + 3) ^ g) * 8];
            for (int e = 0; e < 8; e++) {
                s0 += (float)a0[e] * (float)b0[e];
                s1 += (float)a1[e] * (float)b1[e];
                s2 += (float)a2[e] * (float)b2[e];
                s3 += (float)a3[e] * (float)b3[e];
            }
        }
        float s = ((s0 + s1) + (s2 + s3)) * 0.0625f;
        float m = s;
        for (int off = 1; off < 8; off <<= 1) m = fmaxf(m, __shfl_xor(m, off, 8));
        float p = __expf(s - m);
        float sum = p;
        for (int off = 1; off < 8; off <<= 1) sum += __shfl_xor(sum, off, 8);
        p /= sum;

        float pv[8];
        for (int g2 = 0; g2 < 8; g2++) pv[g2] = __shfl(p, h * 8 + g2, 64);

        WAIT_VM(0);   // v resident (had score+softmax time to arrive)

        float acc[4][8] = {};
        for (int g2 = 0; g2 < 8; g2++) {
            float pw = pv[g2];
            const bf16* vrow = sq + (16 + g2) * 256;
            for (int mm = 0; mm < 4; mm++) {
                bf16x8 v = *(const bf16x8*)&vrow[((g ^ g2) + 8 * mm) * 8];
                for (int e = 0; e < 8; e++) acc[mm][e] += pw * (float)v[e];
            }
        }
        bf16* obase = base + h * D_;
        for (int mm = 0; mm < 4; mm++) {
            bf16x8 o;
            for (int e = 0; e < 8; e++) o[e] = (bf16)acc[mm][e];
            *(bf16x8*)&obase[(g + 8 * mm) * 8] = o;
        }
    }
}

// ---------------------------------------------------------------------------
// Kernel 3: out = attn_out @ Wo + bo  (unchanged from round 8)
// ---------------------------------------------------------------------------
__global__ __launch_bounds__(256) void out_gemm(
    const bf16* __restrict__ qkv, const bf16* __restrict__ WoT,
    const bf16* __restrict__ bob, float* __restrict__ outp)
{
    __shared__ bf16 As[128 * 128];
    __shared__ bf16 Bs[128 * 128];
    int m0 = blockIdx.y * 128, n0 = blockIdx.x * 128;
    int tid = threadIdx.x, wave = tid >> 6, lane = tid & 63;
    int wm = (wave >> 1) * 64, wn = (wave & 1) * 64;
    int mrow = lane & 15, quad = lane >> 4;
    int lrow16 = lane >> 4, lslot16 = lane & 15;

    f32x4 acc[4][4] = {};
    for (int k0 = 0; k0 < HD; k0 += 128) {
        __syncthreads();
        for (int i = 0; i < 8; i++) {
            int rbase = wave * 32 + i * 4;
            int row = rbase + lrow16;
            int gc = lslot16 ^ (row & 7);
            GLDS16(&qkv[(size_t)(m0 + row) * QKVN + k0 + gc * 8], &As[rbase * 128]);
        }
        for (int i = 0; i < 8; i++) {
            int rbase = wave * 32 + i * 4;
            int row = rbase + lrow16;
            int gc = lslot16 ^ (row & 7);
            GLDS16(&WoT[(size_t)(n0 + row) * HD + k0 + gc * 8], &Bs[rbase * 128]);
        }
        __syncthreads();
        for (int kk = 0; kk < 128; kk += 32) {
            int slot = (((kk >> 3) + quad) ^ (mrow & 7)) * 8;
            bf16x8 af[4], bfv[4];
            for (int mt = 0; mt < 4; mt++)
                af[mt] = *(const bf16x8*)&As[(wm + mt * 16 + mrow) * 128 + slot];
            for (int nt = 0; nt < 4; nt++)
                bfv[nt] = *(const bf16x8*)&Bs[(wn + nt * 16 + mrow) * 128 + slot];
            for (int mt = 0; mt < 4; mt++)
                for (int nt = 0; nt < 4; nt++)
                    acc[mt][nt] = __builtin_amdgcn_mfma_f32_16x16x32_bf16(
                        bfv[nt], af[mt], acc[mt][nt], 0, 0, 0);
        }
    }

    for (int mt = 0; mt < 4; mt++) {
        int row = m0 + wm + mt * 16 + mrow;
        for (int nt = 0; nt < 4; nt++) {
            int col = n0 + wn + nt * 16 + quad * 4;
            bf16x4 bb = *(const bf16x4*)&bob[col];
            f32x4 o;
            for (int r = 0; r < 4; r++) o[r] = acc[mt][nt][r] + (float)bb[r];
            *(f32x4*)&outp[(size_t)row * D_ + col] = o;
        }
    }
}

// ---------------------------------------------------------------------------
extern "C" void kernel_launch(void* const* d_in, const int* in_sizes, int n_in,
                              void* d_out, int out_size, void* d_ws, size_t ws_size,
                              hipStream_t stream)
{
    const void* x  = d_in[0];
    const void* Wq = d_in[1];
    const void* bq = d_in[2];
    const void* Wk = d_in[3];
    const void* bk = d_in[4];
    const void* Wv = d_in[5];
    const void* bv = d_in[6];
    const void* Wo = d_in[7];
    const void* bo = d_in[8];
    float* out = (float*)d_out;

    char* ws = (char*)d_ws;
    bf16* qkv  = (bf16*)ws;                          // 201326592 B
    bf16* WT   = (bf16*)(ws + 201326592);            // 3145728 B
    bf16* WoT  = (bf16*)(ws + 204472320);            // 1048576 B
    bf16* xb   = (bf16*)(ws + 205520896);            // 8388608 B
    bf16* bqkv = (bf16*)(ws + 213909504);            // 12288 B
    bf16* bob  = (bf16*)(ws + 213921792);            // 512 B
    int*  flag = (int*)(ws + 213922304);

    detect_dtype<<<1, 64, 0, stream>>>(x, flag);

    convert_x<<<4096, 256, 0, stream>>>(x, xb, flag);
    fuse_bias<<<25, 256, 0, stream>>>(bq, bk, bv, bo, bqkv, bob, flag);
    transpose_cvt3<<<dim3(64, 8, 3), 256, 0, stream>>>(Wq, Wk, Wv, WT, flag);
    transpose_cvt<<<dim3(8, 64), 256, 0, stream>>>(Wo, WoT, 2048, 256, flag);

    proj_gemm<<<dim3(48, 128), 256, 0, stream>>>(xb, WT, bqkv, qkv);
    attn<<<1024, 256, 0, stream>>>(qkv);
    out_gemm<<<dim3(2, 128), 256, 0, stream>>>(qkv, WoT, bob, out);
}

// Round 10
// 257.293 us; speedup vs baseline: 1.2532x; 1.0782x over previous
//
#include <hip/hip_runtime.h>
#include <hip/hip_bf16.h>
#include <math.h>

typedef __bf16 bf16;
typedef __bf16 bf16x4 __attribute__((ext_vector_type(4)));
typedef __bf16 bf16x8 __attribute__((ext_vector_type(8)));
typedef float f32x4 __attribute__((ext_vector_type(4)));
typedef unsigned int u32;
typedef u32 __attribute__((address_space(1))) gu32;
typedef u32 __attribute__((address_space(3))) lu32;

#define TOK   16384
#define D_    256
#define HD    2048
#define QKVN  6144

#define GLDS16(g, l) __builtin_amdgcn_global_load_lds((gu32*)(g), (lu32*)(l), 16, 0, 0)
// s_waitcnt imm: vmcnt[3:0] | expcnt<<4 | lgkmcnt<<8  (expcnt=7,lgkm=15 -> no wait)
#define WAIT_VM(n) __builtin_amdgcn_s_waitcnt(0x0F70 | (n))

// ---------------------------------------------------------------------------
// Dtype probe
// ---------------------------------------------------------------------------
__global__ void detect_dtype(const void* __restrict__ x, int* __restrict__ flag)
{
    int lane = threadIdx.x;
    const bf16* xb = (const bf16*)x;
    float m = 0.f;
    for (int i = lane; i < 4096; i += 64) {
        float v = fabsf((float)xb[2 * i]);
        if (!(v < 1e4f)) v = 1e30f;
        m = fmaxf(m, v);
    }
    for (int off = 32; off; off >>= 1) m = fmaxf(m, __shfl_xor(m, off, 64));
    if (lane == 0) *flag = (m > 1e4f) ? 1 : 0;
}

__global__ __launch_bounds__(256) void convert_x(
    const void* __restrict__ src, bf16* __restrict__ dst,
    const int* __restrict__ flag)
{
    int i = blockIdx.x * 256 + threadIdx.x;
    bf16x4 o;
    if (*flag) {
        f32x4 v = ((const f32x4*)src)[i];
        for (int e = 0; e < 4; e++) o[e] = (bf16)v[e];
    } else {
        o = ((const bf16x4*)src)[i];
    }
    ((bf16x4*)dst)[i] = o;
}

__global__ __launch_bounds__(256) void fuse_bias(
    const void* __restrict__ bq, const void* __restrict__ bk,
    const void* __restrict__ bv, const void* __restrict__ bo,
    bf16* __restrict__ bqkv, bf16* __restrict__ bob,
    const int* __restrict__ flag)
{
    int i = blockIdx.x * 256 + threadIdx.x;
    if (i >= 6400) return;
    const void* src; bf16* dst; int off;
    if (i < 2048)      { src = bq; dst = bqkv;        off = i; }
    else if (i < 4096) { src = bk; dst = bqkv + 2048; off = i - 2048; }
    else if (i < 6144) { src = bv; dst = bqkv + 4096; off = i - 4096; }
    else               { src = bo; dst = bob;         off = i - 6144; }
    float v = (*flag) ? ((const float*)src)[off] : (float)((const bf16*)src)[off];
    dst[off] = (bf16)v;
}

__global__ __launch_bounds__(256) void transpose_cvt3(
    const void* __restrict__ Wq, const void* __restrict__ Wk,
    const void* __restrict__ Wv, bf16* __restrict__ WT,
    const int* __restrict__ flag)
{
    __shared__ float tile[32][33];
    int z = blockIdx.z;
    const void* src = (z == 0) ? Wq : (z == 1) ? Wk : Wv;
    bf16* dst = WT + (size_t)z * 2048 * 256;
    int f = *flag;
    int R = 256, C = 2048;
    int tc = blockIdx.x * 32, tr = blockIdx.y * 32;
    int lx = threadIdx.x & 31, ly = threadIdx.x >> 5;
    for (int i = 0; i < 4; i++) {
        int r = ly + i * 8;
        size_t idx = (size_t)(tr + r) * C + tc + lx;
        tile[r][lx] = f ? ((const float*)src)[idx] : (float)((const bf16*)src)[idx];
    }
    __syncthreads();
    for (int i = 0; i < 4; i++) {
        int r = ly + i * 8;
        dst[(size_t)(tc + r) * R + tr + lx] = (bf16)tile[lx][r];
    }
}

__global__ __launch_bounds__(256) void transpose_cvt(
    const void* __restrict__ src, bf16* __restrict__ dst, int R, int C,
    const int* __restrict__ flag)
{
    __shared__ float tile[32][33];
    int f = *flag;
    int tc = blockIdx.x * 32, tr = blockIdx.y * 32;
    int lx = threadIdx.x & 31, ly = threadIdx.x >> 5;
    for (int i = 0; i < 4; i++) {
        int r = ly + i * 8;
        size_t idx = (size_t)(tr + r) * C + tc + lx;
        tile[r][lx] = f ? ((const float*)src)[idx] : (float)((const bf16*)src)[idx];
    }
    __syncthreads();
    for (int i = 0; i < 4; i++) {
        int r = ly + i * 8;
        dst[(size_t)(tc + r) * R + tr + lx] = (bf16)tile[lx][r];
    }
}

// ---------------------------------------------------------------------------
// Kernel 1: qkv = x @ [Wq|Wk|Wv] + bias  (unchanged from round 9 — 69 us,
// near its write-stream floor: 201 MB @ ~3.5 TB/s)
// ---------------------------------------------------------------------------
__global__ __launch_bounds__(256) void proj_gemm(
    const bf16* __restrict__ X, const bf16* __restrict__ WT,
    const bf16* __restrict__ bqkv, bf16* __restrict__ qkv)
{
    __shared__ char smem[36864];               // union: As+Bs (32K) / epi (36K)
    bf16* As = (bf16*)smem;                    // 128*64
    bf16* Bs = (bf16*)(smem + 16384);          // 128*64
    int m0 = blockIdx.y * 128, n0 = blockIdx.x * 128;
    int tid = threadIdx.x, wave = tid >> 6, lane = tid & 63;
    int wm = (wave >> 1) * 64, wn = (wave & 1) * 64;
    int mrow = lane & 15, quad = lane >> 4;
    int lrow8 = lane >> 3, lslot = lane & 7;

    f32x4 acc[4][4] = {};
    for (int k0 = 0; k0 < D_; k0 += 64) {
        __syncthreads();
        for (int i = 0; i < 4; i++) {
            int rbase = wave * 32 + i * 8;
            int row = rbase + lrow8;
            int gc = lslot ^ (row & 7);
            GLDS16(&X[(size_t)(m0 + row) * D_ + k0 + gc * 8], &As[rbase * 64]);
            GLDS16(&WT[(size_t)(n0 + row) * D_ + k0 + gc * 8], &Bs[rbase * 64]);
        }
        __syncthreads();
        for (int kk = 0; kk < 64; kk += 32) {
            int slot = (((kk >> 3) + quad) ^ (mrow & 7)) * 8;
            bf16x8 af[4], bfv[4];
            for (int mt = 0; mt < 4; mt++)
                af[mt] = *(const bf16x8*)&As[(wm + mt * 16 + mrow) * 64 + slot];
            for (int nt = 0; nt < 4; nt++)
                bfv[nt] = *(const bf16x8*)&Bs[(wn + nt * 16 + mrow) * 64 + slot];
            for (int mt = 0; mt < 4; mt++)
                for (int nt = 0; nt < 4; nt++)
                    acc[mt][nt] = __builtin_amdgcn_mfma_f32_16x16x32_bf16(
                        bfv[nt], af[mt], acc[mt][nt], 0, 0, 0);
        }
    }

    __syncthreads();
    bf16* ep = (bf16*)smem + wave * (64 * 72);
    for (int mt = 0; mt < 4; mt++) {
        for (int nt = 0; nt < 4; nt++) {
            int col = n0 + wn + nt * 16 + quad * 4;
            bf16x4 bb = *(const bf16x4*)&bqkv[col];
            bf16x4 o;
            for (int r = 0; r < 4; r++) o[r] = (bf16)(acc[mt][nt][r] + (float)bb[r]);
            *(bf16x4*)&ep[(mt * 16 + mrow) * 72 + nt * 16 + quad * 4] = o;
        }
    }
    __syncthreads();
    for (int i = 0; i < 8; i++) {
        int r = i * 8 + (lane >> 3);
        int cb = (lane & 7) * 8;
        bf16x8 val = *(const bf16x8*)&ep[r * 72 + cb];
        *(bf16x8*)&qkv[(size_t)(m0 + wm + r) * QKVN + n0 + wn + cb] = val;
    }
}

// ---------------------------------------------------------------------------
// Kernel 2: per-token 8x8 attention — PERSISTENT grid (768 blocks = exactly
// 3 blocks/CU at 48 KB LDS, no dispatch tail). Waves take 5-6 tokens each
// (first 1024 waves: 6, rest: 5; contiguous, uniform within wave).
// Split vmcnt waits + XOR swizzle + 4-acc ILP (r9-verified inner body).
// ---------------------------------------------------------------------------
__global__ __launch_bounds__(256) void attn(bf16* __restrict__ qkv)
{
    __shared__ bf16 sh[4][6144];   // per wave: rows 0-7 q, 8-15 k, 16-23 v
    int wave = threadIdx.x >> 6, lane = threadIdx.x & 63;
    bf16* sq = sh[wave];
    int h = lane >> 3, g = lane & 7;
    int wid = blockIdx.x * 4 + wave;               // 0..3071
    int start = (wid < 1024) ? wid * 6 : 6144 + (wid - 1024) * 5;
    int count = (wid < 1024) ? 6 : 5;

    for (int ti = 0; ti < count; ti++) {
        int t = start + ti;
        bf16* base = qkv + (size_t)t * QKVN;
        // 12 glds: i 0-7 -> q+k rows 0-15; i 8-11 -> v rows 16-23
        for (int i = 0; i < 12; i++) {
            int s = i * 64 + lane;
            int row = s >> 5, cs = s & 31;
            int gc = cs ^ (row & 7);
            GLDS16(base + row * 256 + gc * 8, (char*)sq + i * 1024);
        }
        WAIT_VM(4);   // q+k resident; v (4 newest) still in flight

        const bf16* qrow = sq + h * 256;
        const bf16* krow = sq + (8 + g) * 256;
        float s0 = 0.f, s1 = 0.f, s2 = 0.f, s3 = 0.f;
        for (int c = 0; c < 32; c += 4) {
            bf16x8 a0 = *(const bf16x8*)&qrow[((c + 0) ^ h) * 8];
            bf16x8 b0 = *(const bf16x8*)&krow[((c + 0) ^ g) * 8];
            bf16x8 a1 = *(const bf16x8*)&qrow[((c + 1) ^ h) * 8];
            bf16x8 b1 = *(const bf16x8*)&krow[((c + 1) ^ g) * 8];
            bf16x8 a2 = *(const bf16x8*)&qrow[((c + 2) ^ h) * 8];
            bf16x8 b2 = *(const bf16x8*)&krow[((c + 2) ^ g) * 8];
            bf16x8 a3 = *(const bf16x8*)&qrow[((c + 3) ^ h) * 8];
            bf16x8 b3 = *(const bf16x8*)&krow[((c + 3) ^ g) * 8];
            for (int e = 0; e < 8; e++) {
                s0 += (float)a0[e] * (float)b0[e];
                s1 += (float)a1[e] * (float)b1[e];
                s2 += (float)a2[e] * (float)b2[e];
                s3 += (float)a3[e] * (float)b3[e];
            }
        }
        float s = ((s0 + s1) + (s2 + s3)) * 0.0625f;
        float m = s;
        for (int off = 1; off < 8; off <<= 1) m = fmaxf(m, __shfl_xor(m, off, 8));
        float p = __expf(s - m);
        float sum = p;
        for (int off = 1; off < 8; off <<= 1) sum += __shfl_xor(sum, off, 8);
        p /= sum;

        float pv[8];
        for (int g2 = 0; g2 < 8; g2++) pv[g2] = __shfl(p, h * 8 + g2, 64);

        WAIT_VM(0);   // v resident (had score+softmax time to arrive)

        float acc[4][8] = {};
        for (int g2 = 0; g2 < 8; g2++) {
            float pw = pv[g2];
            const bf16* vrow = sq + (16 + g2) * 256;
            for (int mm = 0; mm < 4; mm++) {
                bf16x8 v = *(const bf16x8*)&vrow[((g ^ g2) + 8 * mm) * 8];
                for (int e = 0; e < 8; e++) acc[mm][e] += pw * (float)v[e];
            }
        }
        bf16* obase = base + h * D_;
        for (int mm = 0; mm < 4; mm++) {
            bf16x8 o;
            for (int e = 0; e < 8; e++) o[e] = (bf16)acc[mm][e];
            *(bf16x8*)&obase[(g + 8 * mm) * 8] = o;
        }
    }
}

// ---------------------------------------------------------------------------
// Kernel 3: out = attn_out @ Wo + bo  (M=16384, K=2048, N=256), fp32 out.
// RESTRUCTURED: 64x128 tile, BK=128, grid (2,256)=512 blocks, 48 KB LDS ->
// 2 resident blocks/CU (was 256 blocks = 1/CU, 12.5% occupancy).
// ---------------------------------------------------------------------------
__global__ __launch_bounds__(256) void out_gemm(
    const bf16* __restrict__ qkv, const bf16* __restrict__ WoT,
    const bf16* __restrict__ bob, float* __restrict__ outp)
{
    __shared__ bf16 As[64 * 128];    // 16 KB
    __shared__ bf16 Bs[128 * 128];   // 32 KB
    int m0 = blockIdx.y * 64, n0 = blockIdx.x * 128;
    int tid = threadIdx.x, wave = tid >> 6, lane = tid & 63;
    int wm = (wave >> 1) * 32, wn = (wave & 1) * 64;
    int mrow = lane & 15, quad = lane >> 4;
    int lrow16 = lane >> 4, lslot16 = lane & 15;

    f32x4 acc[2][4] = {};
    for (int k0 = 0; k0 < HD; k0 += 128) {
        __syncthreads();
        for (int i = 0; i < 4; i++) {            // A: wave stages 16 rows
            int rbase = wave * 16 + i * 4;
            int row = rbase + lrow16;
            int gc = lslot16 ^ (row & 7);
            GLDS16(&qkv[(size_t)(m0 + row) * QKVN + k0 + gc * 8], &As[rbase * 128]);
        }
        for (int i = 0; i < 8; i++) {            // B: wave stages 32 rows
            int rbase = wave * 32 + i * 4;
            int row = rbase + lrow16;
            int gc = lslot16 ^ (row & 7);
            GLDS16(&WoT[(size_t)(n0 + row) * HD + k0 + gc * 8], &Bs[rbase * 128]);
        }
        __syncthreads();
        for (int kk = 0; kk < 128; kk += 32) {
            int slot = (((kk >> 3) + quad) ^ (mrow & 7)) * 8;
            bf16x8 af[2], bfv[4];
            for (int mt = 0; mt < 2; mt++)
                af[mt] = *(const bf16x8*)&As[(wm + mt * 16 + mrow) * 128 + slot];
            for (int nt = 0; nt < 4; nt++)
                bfv[nt] = *(const bf16x8*)&Bs[(wn + nt * 16 + mrow) * 128 + slot];
            for (int mt = 0; mt < 2; mt++)
                for (int nt = 0; nt < 4; nt++)
                    acc[mt][nt] = __builtin_amdgcn_mfma_f32_16x16x32_bf16(
                        bfv[nt], af[mt], acc[mt][nt], 0, 0, 0);
        }
    }

    for (int mt = 0; mt < 2; mt++) {
        int row = m0 + wm + mt * 16 + mrow;
        for (int nt = 0; nt < 4; nt++) {
            int col = n0 + wn + nt * 16 + quad * 4;
            bf16x4 bb = *(const bf16x4*)&bob[col];
            f32x4 o;
            for (int r = 0; r < 4; r++) o[r] = acc[mt][nt][r] + (float)bb[r];
            *(f32x4*)&outp[(size_t)row * D_ + col] = o;
        }
    }
}

// ---------------------------------------------------------------------------
extern "C" void kernel_launch(void* const* d_in, const int* in_sizes, int n_in,
                              void* d_out, int out_size, void* d_ws, size_t ws_size,
                              hipStream_t stream)
{
    const void* x  = d_in[0];
    const void* Wq = d_in[1];
    const void* bq = d_in[2];
    const void* Wk = d_in[3];
    const void* bk = d_in[4];
    const void* Wv = d_in[5];
    const void* bv = d_in[6];
    const void* Wo = d_in[7];
    const void* bo = d_in[8];
    float* out = (float*)d_out;

    char* ws = (char*)d_ws;
    bf16* qkv  = (bf16*)ws;                          // 201326592 B
    bf16* WT   = (bf16*)(ws + 201326592);            // 3145728 B
    bf16* WoT  = (bf16*)(ws + 204472320);            // 1048576 B
    bf16* xb   = (bf16*)(ws + 205520896);            // 8388608 B
    bf16* bqkv = (bf16*)(ws + 213909504);            // 12288 B
    bf16* bob  = (bf16*)(ws + 213921792);            // 512 B
    int*  flag = (int*)(ws + 213922304);

    detect_dtype<<<1, 64, 0, stream>>>(x, flag);

    convert_x<<<4096, 256, 0, stream>>>(x, xb, flag);
    fuse_bias<<<25, 256, 0, stream>>>(bq, bk, bv, bo, bqkv, bob, flag);
    transpose_cvt3<<<dim3(64, 8, 3), 256, 0, stream>>>(Wq, Wk, Wv, WT, flag);
    transpose_cvt<<<dim3(8, 64), 256, 0, stream>>>(Wo, WoT, 2048, 256, flag);

    proj_gemm<<<dim3(48, 128), 256, 0, stream>>>(xb, WT, bqkv, qkv);
    attn<<<768, 256, 0, stream>>>(qkv);
    out_gemm<<<dim3(2, 256), 256, 0, stream>>>(qkv, WoT, bob, out);
}

// Round 11
// 236.551 us; speedup vs baseline: 1.3631x; 1.0877x over previous
//
#include <hip/hip_runtime.h>
#include <hip/hip_bf16.h>
#include <math.h>

typedef __bf16 bf16;
typedef __bf16 bf16x4 __attribute__((ext_vector_type(4)));
typedef __bf16 bf16x8 __attribute__((ext_vector_type(8)));
typedef float f32x4 __attribute__((ext_vector_type(4)));
typedef unsigned int u32;
typedef u32 __attribute__((address_space(1))) gu32;
typedef u32 __attribute__((address_space(3))) lu32;

#define TOK   16384
#define D_    256
#define HD    2048
#define QKVN  6144

#define GLDS16(g, l) __builtin_amdgcn_global_load_lds((gu32*)(g), (lu32*)(l), 16, 0, 0)
// s_waitcnt imm: vmcnt[3:0] | expcnt<<4 | lgkmcnt<<8  (expcnt=7,lgkm=15 -> no wait)
#define WAIT_VM(n) __builtin_amdgcn_s_waitcnt(0x0F70 | (n))

// ---------------------------------------------------------------------------
// ONE prep kernel: roles by blockIdx.x. Dtype flag computed block-locally
// (256 even-element samples of x; fp32-as-bf16 => ~45%/elem chance of huge
// exponent, miss prob 0.55^256 ~ 1e-66) -- no inter-kernel dependency.
//   b <  4096: convert x (4 elems/thread)
//   b <  4121: biases bq|bk|bv -> bqkv, bo -> bob
//   b <  5657: transpose Wq/Wk/Wv (256x2048 -> 2048x256), z = (b-4121)/512
//   b <  6169: transpose Wo (2048x256 -> 256x2048)
// ---------------------------------------------------------------------------
__device__ __forceinline__ void transpose_body(
    const void* __restrict__ src, bf16* __restrict__ dst, int R, int C,
    int tc, int tr, int f, float (*tile)[33])
{
    int lx = threadIdx.x & 31, ly = threadIdx.x >> 5;
    for (int i = 0; i < 4; i++) {
        int r = ly + i * 8;
        size_t idx = (size_t)(tr + r) * C + tc + lx;
        tile[r][lx] = f ? ((const float*)src)[idx] : (float)((const bf16*)src)[idx];
    }
    __syncthreads();
    for (int i = 0; i < 4; i++) {
        int r = ly + i * 8;
        dst[(size_t)(tc + r) * R + tr + lx] = (bf16)tile[lx][r];
    }
}

__global__ __launch_bounds__(256) void prep(
    const void* __restrict__ x,
    const void* __restrict__ Wq, const void* __restrict__ bq,
    const void* __restrict__ Wk, const void* __restrict__ bk,
    const void* __restrict__ Wv, const void* __restrict__ bv,
    const void* __restrict__ Wo, const void* __restrict__ bo,
    bf16* __restrict__ xb, bf16* __restrict__ WT, bf16* __restrict__ WoT,
    bf16* __restrict__ bqkv, bf16* __restrict__ bob)
{
    __shared__ float tile[32][33];
    __shared__ int sflag;
    int tid = threadIdx.x;
    if (tid == 0) sflag = 0;
    __syncthreads();
    {
        float v = fabsf((float)((const bf16*)x)[2 * tid]);
        if (!(v < 1e4f)) sflag = 1;   // benign race, all writers store 1
    }
    __syncthreads();
    int f = sflag;
    int b = blockIdx.x;

    if (b < 4096) {                               // convert x
        int i = b * 256 + tid;
        bf16x4 o;
        if (f) { f32x4 v = ((const f32x4*)x)[i]; for (int e = 0; e < 4; e++) o[e] = (bf16)v[e]; }
        else   { o = ((const bf16x4*)x)[i]; }
        ((bf16x4*)xb)[i] = o;
    } else if (b < 4121) {                        // biases
        int i = (b - 4096) * 256 + tid;
        if (i < 6400) {
            const void* src; bf16* dst; int off;
            if (i < 2048)      { src = bq; dst = bqkv;        off = i; }
            else if (i < 4096) { src = bk; dst = bqkv + 2048; off = i - 2048; }
            else if (i < 6144) { src = bv; dst = bqkv + 4096; off = i - 4096; }
            else               { src = bo; dst = bob;         off = i - 6144; }
            float v = f ? ((const float*)src)[off] : (float)((const bf16*)src)[off];
            dst[off] = (bf16)v;
        }
        __syncthreads();                          // match transpose barrier count
    } else if (b < 5657) {                        // Wq/Wk/Wv transpose
        int idx = b - 4121;                       // 0..1535
        int tx = idx & 63, rest = idx >> 6;
        int ty = rest & 7, tz = rest >> 3;
        const void* src = (tz == 0) ? Wq : (tz == 1) ? Wk : Wv;
        bf16* dst = WT + (size_t)tz * 2048 * 256;
        transpose_body(src, dst, 256, 2048, tx * 32, ty * 32, f, tile);
    } else {                                      // Wo transpose
        int idx = b - 5657;                       // 0..511
        int tx = idx & 7, ty = idx >> 3;
        transpose_body(Wo, WoT, 2048, 256, tx * 32, ty * 32, f, tile);
    }
}

// ---------------------------------------------------------------------------
// Kernel 1: qkv = x @ [Wq|Wk|Wv] + bias  (unchanged from r9 — 69 us, pinned
// at its write-stream floor: 201 MB @ ~3.5 TB/s; 3 shape probes all equal)
// ---------------------------------------------------------------------------
__global__ __launch_bounds__(256) void proj_gemm(
    const bf16* __restrict__ X, const bf16* __restrict__ WT,
    const bf16* __restrict__ bqkv, bf16* __restrict__ qkv)
{
    __shared__ char smem[36864];               // union: As+Bs (32K) / epi (36K)
    bf16* As = (bf16*)smem;                    // 128*64
    bf16* Bs = (bf16*)(smem + 16384);          // 128*64
    int m0 = blockIdx.y * 128, n0 = blockIdx.x * 128;
    int tid = threadIdx.x, wave = tid >> 6, lane = tid & 63;
    int wm = (wave >> 1) * 64, wn = (wave & 1) * 64;
    int mrow = lane & 15, quad = lane >> 4;
    int lrow8 = lane >> 3, lslot = lane & 7;

    f32x4 acc[4][4] = {};
    for (int k0 = 0; k0 < D_; k0 += 64) {
        __syncthreads();
        for (int i = 0; i < 4; i++) {
            int rbase = wave * 32 + i * 8;
            int row = rbase + lrow8;
            int gc = lslot ^ (row & 7);
            GLDS16(&X[(size_t)(m0 + row) * D_ + k0 + gc * 8], &As[rbase * 64]);
            GLDS16(&WT[(size_t)(n0 + row) * D_ + k0 + gc * 8], &Bs[rbase * 64]);
        }
        __syncthreads();
        for (int kk = 0; kk < 64; kk += 32) {
            int slot = (((kk >> 3) + quad) ^ (mrow & 7)) * 8;
            bf16x8 af[4], bfv[4];
            for (int mt = 0; mt < 4; mt++)
                af[mt] = *(const bf16x8*)&As[(wm + mt * 16 + mrow) * 64 + slot];
            for (int nt = 0; nt < 4; nt++)
                bfv[nt] = *(const bf16x8*)&Bs[(wn + nt * 16 + mrow) * 64 + slot];
            for (int mt = 0; mt < 4; mt++)
                for (int nt = 0; nt < 4; nt++)
                    acc[mt][nt] = __builtin_amdgcn_mfma_f32_16x16x32_bf16(
                        bfv[nt], af[mt], acc[mt][nt], 0, 0, 0);
        }
    }

    __syncthreads();
    bf16* ep = (bf16*)smem + wave * (64 * 72);
    for (int mt = 0; mt < 4; mt++) {
        for (int nt = 0; nt < 4; nt++) {
            int col = n0 + wn + nt * 16 + quad * 4;
            bf16x4 bb = *(const bf16x4*)&bqkv[col];
            bf16x4 o;
            for (int r = 0; r < 4; r++) o[r] = (bf16)(acc[mt][nt][r] + (float)bb[r]);
            *(bf16x4*)&ep[(mt * 16 + mrow) * 72 + nt * 16 + quad * 4] = o;
        }
    }
    __syncthreads();
    for (int i = 0; i < 8; i++) {
        int r = i * 8 + (lane >> 3);
        int cb = (lane & 7) * 8;
        bf16x8 val = *(const bf16x8*)&ep[r * 72 + cb];
        *(bf16x8*)&qkv[(size_t)(m0 + wm + r) * QKVN + n0 + wn + cb] = val;
    }
}

// ---------------------------------------------------------------------------
// Kernel 2: per-token 8x8 attention (unchanged from r10: persistent 768
// blocks = 3/CU, split vmcnt waits, XOR swizzle, 4-acc ILP)
// ---------------------------------------------------------------------------
__global__ __launch_bounds__(256) void attn(bf16* __restrict__ qkv)
{
    __shared__ bf16 sh[4][6144];   // per wave: rows 0-7 q, 8-15 k, 16-23 v
    int wave = threadIdx.x >> 6, lane = threadIdx.x & 63;
    bf16* sq = sh[wave];
    int h = lane >> 3, g = lane & 7;
    int wid = blockIdx.x * 4 + wave;               // 0..3071
    int start = (wid < 1024) ? wid * 6 : 6144 + (wid - 1024) * 5;
    int count = (wid < 1024) ? 6 : 5;

    for (int ti = 0; ti < count; ti++) {
        int t = start + ti;
        bf16* base = qkv + (size_t)t * QKVN;
        for (int i = 0; i < 12; i++) {
            int s = i * 64 + lane;
            int row = s >> 5, cs = s & 31;
            int gc = cs ^ (row & 7);
            GLDS16(base + row * 256 + gc * 8, (char*)sq + i * 1024);
        }
        WAIT_VM(4);   // q+k resident; v (4 newest) still in flight

        const bf16* qrow = sq + h * 256;
        const bf16* krow = sq + (8 + g) * 256;
        float s0 = 0.f, s1 = 0.f, s2 = 0.f, s3 = 0.f;
        for (int c = 0; c < 32; c += 4) {
            bf16x8 a0 = *(const bf16x8*)&qrow[((c + 0) ^ h) * 8];
            bf16x8 b0 = *(const bf16x8*)&krow[((c + 0) ^ g) * 8];
            bf16x8 a1 = *(const bf16x8*)&qrow[((c + 1) ^ h) * 8];
            bf16x8 b1 = *(const bf16x8*)&krow[((c + 1) ^ g) * 8];
            bf16x8 a2 = *(const bf16x8*)&qrow[((c + 2) ^ h) * 8];
            bf16x8 b2 = *(const bf16x8*)&krow[((c + 2) ^ g) * 8];
            bf16x8 a3 = *(const bf16x8*)&qrow[((c + 3) ^ h) * 8];
            bf16x8 b3 = *(const bf16x8*)&krow[((c + 3) ^ g) * 8];
            for (int e = 0; e < 8; e++) {
                s0 += (float)a0[e] * (float)b0[e];
                s1 += (float)a1[e] * (float)b1[e];
                s2 += (float)a2[e] * (float)b2[e];
                s3 += (float)a3[e] * (float)b3[e];
            }
        }
        float s = ((s0 + s1) + (s2 + s3)) * 0.0625f;
        float m = s;
        for (int off = 1; off < 8; off <<= 1) m = fmaxf(m, __shfl_xor(m, off, 8));
        float p = __expf(s - m);
        float sum = p;
        for (int off = 1; off < 8; off <<= 1) sum += __shfl_xor(sum, off, 8);
        p /= sum;

        float pv[8];
        for (int g2 = 0; g2 < 8; g2++) pv[g2] = __shfl(p, h * 8 + g2, 64);

        WAIT_VM(0);   // v resident (had score+softmax time to arrive)

        float acc[4][8] = {};
        for (int g2 = 0; g2 < 8; g2++) {
            float pw = pv[g2];
            const bf16* vrow = sq + (16 + g2) * 256;
            for (int mm = 0; mm < 4; mm++) {
                bf16x8 v = *(const bf16x8*)&vrow[((g ^ g2) + 8 * mm) * 8];
                for (int e = 0; e < 8; e++) acc[mm][e] += pw * (float)v[e];
            }
        }
        bf16* obase = base + h * D_;
        for (int mm = 0; mm < 4; mm++) {
            bf16x8 o;
            for (int e = 0; e < 8; e++) o[e] = (bf16)acc[mm][e];
            *(bf16x8*)&obase[(g + 8 * mm) * 8] = o;
        }
    }
}

// ---------------------------------------------------------------------------
// Kernel 3: out = attn_out @ Wo + bo  (M=16384, K=2048, N=256), fp32 out.
// 32x128 tile, BK=128, grid (2,512)=1024 blocks, 40 KB LDS -> 4 blocks/CU
// (r10's 512 blocks were grid-capped at 2/CU).
// ---------------------------------------------------------------------------
__global__ __launch_bounds__(256) void out_gemm(
    const bf16* __restrict__ qkv, const bf16* __restrict__ WoT,
    const bf16* __restrict__ bob, float* __restrict__ outp)
{
    __shared__ bf16 As[32 * 128];    // 8 KB
    __shared__ bf16 Bs[128 * 128];   // 32 KB
    int m0 = blockIdx.y * 32, n0 = blockIdx.x * 128;
    int tid = threadIdx.x, wave = tid >> 6, lane = tid & 63;
    int wm = (wave >> 1) * 16, wn = (wave & 1) * 64;
    int mrow = lane & 15, quad = lane >> 4;
    int lrow16 = lane >> 4, lslot16 = lane & 15;

    f32x4 acc[4] = {};
    for (int k0 = 0; k0 < HD; k0 += 128) {
        __syncthreads();
        for (int i = 0; i < 2; i++) {            // A: wave stages 8 rows
            int rbase = wave * 8 + i * 4;
            int row = rbase + lrow16;
            int gc = lslot16 ^ (row & 7);
            GLDS16(&qkv[(size_t)(m0 + row) * QKVN + k0 + gc * 8], &As[rbase * 128]);
        }
        for (int i = 0; i < 8; i++) {            // B: wave stages 32 rows
            int rbase = wave * 32 + i * 4;
            int row = rbase + lrow16;
            int gc = lslot16 ^ (row & 7);
            GLDS16(&WoT[(size_t)(n0 + row) * HD + k0 + gc * 8], &Bs[rbase * 128]);
        }
        __syncthreads();
        for (int kk = 0; kk < 128; kk += 32) {
            int slot = (((kk >> 3) + quad) ^ (mrow & 7)) * 8;
            bf16x8 af = *(const bf16x8*)&As[(wm + mrow) * 128 + slot];
            bf16x8 bfv[4];
            for (int nt = 0; nt < 4; nt++)
                bfv[nt] = *(const bf16x8*)&Bs[(wn + nt * 16 + mrow) * 128 + slot];
            for (int nt = 0; nt < 4; nt++)
                acc[nt] = __builtin_amdgcn_mfma_f32_16x16x32_bf16(
                    bfv[nt], af, acc[nt], 0, 0, 0);
        }
    }

    int row = m0 + wm + mrow;
    for (int nt = 0; nt < 4; nt++) {
        int col = n0 + wn + nt * 16 + quad * 4;
        bf16x4 bb = *(const bf16x4*)&bob[col];
        f32x4 o;
        for (int r = 0; r < 4; r++) o[r] = acc[nt][r] + (float)bb[r];
        *(f32x4*)&outp[(size_t)row * D_ + col] = o;
    }
}

// ---------------------------------------------------------------------------
extern "C" void kernel_launch(void* const* d_in, const int* in_sizes, int n_in,
                              void* d_out, int out_size, void* d_ws, size_t ws_size,
                              hipStream_t stream)
{
    const void* x  = d_in[0];
    const void* Wq = d_in[1];
    const void* bq = d_in[2];
    const void* Wk = d_in[3];
    const void* bk = d_in[4];
    const void* Wv = d_in[5];
    const void* bv = d_in[6];
    const void* Wo = d_in[7];
    const void* bo = d_in[8];
    float* out = (float*)d_out;

    char* ws = (char*)d_ws;
    bf16* qkv  = (bf16*)ws;                          // 201326592 B
    bf16* WT   = (bf16*)(ws + 201326592);            // 3145728 B
    bf16* WoT  = (bf16*)(ws + 204472320);            // 1048576 B
    bf16* xb   = (bf16*)(ws + 205520896);            // 8388608 B
    bf16* bqkv = (bf16*)(ws + 213909504);            // 12288 B
    bf16* bob  = (bf16*)(ws + 213921792);            // 512 B

    prep<<<6169, 256, 0, stream>>>(x, Wq, bq, Wk, bk, Wv, bv, Wo, bo,
                                   xb, WT, WoT, bqkv, bob);
    proj_gemm<<<dim3(48, 128), 256, 0, stream>>>(xb, WT, bqkv, qkv);
    attn<<<768, 256, 0, stream>>>(qkv);
    out_gemm<<<dim3(2, 512), 256, 0, stream>>>(qkv, WoT, bob, out);
}